// Round 7
// baseline (327.088 us; speedup 1.0000x reference)
//
#include <hip/hip_runtime.h>
#include <hip/hip_bf16.h>
#include <math.h>

// B=16, H=W=256, 150 hidden channels, K=20 value-iteration steps.
//
// pack_a_kernel: sign-partitions channels by sign(Wp), scales rows by SIGNED
//   Wp, packs MFMA A-frags (6 groups x 32 rows, zero-pad) + nPosG header.
//   Wp*relu(h) == max(Wp*h,0) for Wp>=0, min(Wp*h,0) for Wp<0.
// conv_p_mfma (R7): NO LDS, NO barriers. A-frags direct from global
//   (L2-resident 6KB). 2-deep MFMA/epilogue pipeline -> ~80 VGPR.
// mvprop_kernel: byte-identical since R2 (~20.6us by subtraction).
// conv_diag / mvprop_diag: x8-repeat copies writing to d_ws scratch, with
//   asm anti-CSE clobbers -> >41us dispatches that surface REAL counters
//   in the top-5 (the harness's 41us poison-fills mask everything below).

#define SENT -1e30f

typedef short short8 __attribute__((ext_vector_type(8)));
typedef float f32x16 __attribute__((ext_vector_type(16)));

__device__ __forceinline__ uint32_t pkbf(float lo, float hi) {
    uint32_t r;
    asm("v_cvt_pk_bf16_f32 %0, %1, %2" : "=v"(r) : "v"(lo), "v"(hi));
    return r;
}

__device__ __forceinline__ uint32_t bfu(float f) {
    __hip_bfloat16 h = __float2bfloat16(f);
    ushort u; __builtin_memcpy(&u, &h, 2);
    return (uint32_t)u;
}

// ---- setup: sign-partition + scale + pack A fragments. grid=1, block=256.
__global__ void pack_a_kernel(const float* __restrict__ Wh,
                              const float* __restrict__ bh,
                              const float* __restrict__ Wp,
                              uint4* __restrict__ wsA)
{
    __shared__ int scan[256];
    const int tid = threadIdx.x;
    const bool valid = tid < 150;
    float wp = valid ? Wp[tid] : 0.f;
    bool pos = valid && (wp >= 0.f);
    bool neg = valid && (wp < 0.f);

    int v = (pos ? 1 : 0) | ((neg ? 1 : 0) << 16);
    scan[tid] = v;
    __syncthreads();
    for (int off = 1; off < 256; off <<= 1) {
        int x = scan[tid];
        int y = (tid >= off) ? scan[tid - off] : 0;
        __syncthreads();
        scan[tid] = x + y;
        __syncthreads();
    }
    int incl  = scan[tid];
    int total = scan[255];
    int P     = total & 0xffff;
    int rankPos = (incl & 0xffff) - (pos ? 1 : 0);
    int rankNeg = (incl >> 16)    - (neg ? 1 : 0);
    int Ppad  = (P + 31) & ~31;
    int nPosG = Ppad >> 5;
    int newidx = pos ? rankPos : (Ppad + rankNeg);

    if (tid < 384) wsA[tid] = make_uint4(0u, 0u, 0u, 0u);
    if (tid == 0)  ((uint32_t*)(wsA + 384))[0] = (uint32_t)nPosG;
    __syncthreads();

    if (valid) {
        float s  = wp;
        float w0 = Wh[tid*9+0]*s, w1 = Wh[tid*9+1]*s, w2 = Wh[tid*9+2]*s;
        float w3 = Wh[tid*9+3]*s, w4 = Wh[tid*9+4]*s, w5 = Wh[tid*9+5]*s;
        float w6 = Wh[tid*9+6]*s, w7 = Wh[tid*9+7]*s, w8 = Wh[tid*9+8]*s;
        float bb = bh[tid]*s;
        int g = newidx >> 5, col0 = newidx & 31;
        uint4 q;
        q.x = (bfu(w1) << 16) | bfu(w0);
        q.y = (bfu(w3) << 16) | bfu(w2);
        q.z = (bfu(w5) << 16) | bfu(w4);
        q.w = (bfu(w7) << 16) | bfu(w6);
        wsA[g * 64 + col0] = q;                 // half 0: k=0..7
        q.x = (bfu(bb) << 16) | bfu(w8);        // half 1: k=8 tap, k=9 bias
        q.y = 0; q.z = 0; q.w = 0;
        wsA[g * 64 + 32 + col0] = q;
    }
}

// shared conv body pieces ------------------------------------------------
#define CONV_PROLOG                                                          \
    const int tid  = threadIdx.x;                                            \
    const int wv   = tid >> 6;                                               \
    const int lane = tid & 63;                                               \
    const int half = lane >> 5;                                              \
    const int col0 = lane & 31;                                              \
    const int b    = blockIdx.z;                                             \
    const int y    = blockIdx.y * 4 + wv;                                    \
    const int px   = blockIdx.x * 32 + col0;                                 \
    const float* occ = image + (size_t)b * 131072;                           \
    uint4 q0 = wsA[0*64+lane], q1 = wsA[1*64+lane], q2 = wsA[2*64+lane];     \
    uint4 q3 = wsA[3*64+lane], q4 = wsA[4*64+lane], q5 = wsA[5*64+lane];     \
    const int nPosG = (int)__builtin_amdgcn_readfirstlane(                   \
        ((const uint32_t*)(wsA + 384))[0]);                                  \
    float t0, t1, t2, t3, t4, t5, t6, t7, t8;                                \
    {                                                                        \
        bool x0ok = (px >= 1), x2ok = (px <= 254);                           \
        int xm = px - 1, xp = px + 1;                                        \
        bool y0ok = (y >= 1), y2ok = (y <= 254);                             \
        const float* rm = occ + (y - 1) * 256;                               \
        const float* rc = occ + y * 256;                                     \
        const float* rp = occ + (y + 1) * 256;                               \
        t0 = (y0ok & x0ok) ? rm[xm] : 0.f;                                   \
        t1 =  y0ok         ? rm[px] : 0.f;                                   \
        t2 = (y0ok & x2ok) ? rm[xp] : 0.f;                                   \
        t3 =  x0ok         ? rc[xm] : 0.f;                                   \
        t4 =                 rc[px];                                         \
        t5 =  x2ok         ? rc[xp] : 0.f;                                   \
        t6 = (y2ok & x0ok) ? rp[xm] : 0.f;                                   \
        t7 =  y2ok         ? rp[px] : 0.f;                                   \
        t8 = (y2ok & x2ok) ? rp[xp] : 0.f;                                   \
    }                                                                        \
    union UA { uint4 q; short8 s; };                                         \
    UA u0, u1, u2, u3, u4, u5;                                               \
    u0.q = q0; u1.q = q1; u2.q = q2; u3.q = q3; u4.q = q4; u5.q = q5;

#define EPI(D, G)                                                            \
    if ((G) < nPosG) {                                                       \
        S0 += fmaxf(D[0],0.f);  S1 += fmaxf(D[1],0.f);                       \
        S2 += fmaxf(D[2],0.f);  S3 += fmaxf(D[3],0.f);                       \
        S0 += fmaxf(D[4],0.f);  S1 += fmaxf(D[5],0.f);                       \
        S2 += fmaxf(D[6],0.f);  S3 += fmaxf(D[7],0.f);                       \
        S0 += fmaxf(D[8],0.f);  S1 += fmaxf(D[9],0.f);                       \
        S2 += fmaxf(D[10],0.f); S3 += fmaxf(D[11],0.f);                      \
        S0 += fmaxf(D[12],0.f); S1 += fmaxf(D[13],0.f);                      \
        S2 += fmaxf(D[14],0.f); S3 += fmaxf(D[15],0.f);                      \
    } else {                                                                 \
        S0 += fminf(D[0],0.f);  S1 += fminf(D[1],0.f);                       \
        S2 += fminf(D[2],0.f);  S3 += fminf(D[3],0.f);                       \
        S0 += fminf(D[4],0.f);  S1 += fminf(D[5],0.f);                       \
        S2 += fminf(D[6],0.f);  S3 += fminf(D[7],0.f);                       \
        S0 += fminf(D[8],0.f);  S1 += fminf(D[9],0.f);                       \
        S2 += fminf(D[10],0.f); S3 += fminf(D[11],0.f);                      \
        S0 += fminf(D[12],0.f); S1 += fminf(D[13],0.f);                      \
        S2 += fminf(D[14],0.f); S3 += fminf(D[15],0.f);                      \
    }

#define CONV_COMPUTE(OUTP)                                                   \
    {                                                                        \
        union { uint32_t u[4]; short8 s; } bb;                               \
        bb.u[0] = half ? pkbf(t8, 1.0f) : pkbf(t0, t1);                      \
        bb.u[1] = half ? 0u : pkbf(t2, t3);                                  \
        bb.u[2] = half ? 0u : pkbf(t4, t5);                                  \
        bb.u[3] = half ? 0u : pkbf(t6, t7);                                  \
        short8 bfr = bb.s;                                                   \
        const f32x16 kZero = {};                                             \
        float S0 = 0.f, S1 = 0.f, S2 = 0.f, S3 = 0.f;                        \
        f32x16 dc, dn;                                                       \
        dc = __builtin_amdgcn_mfma_f32_32x32x16_bf16(u0.s, bfr, kZero,0,0,0);\
        dn = __builtin_amdgcn_mfma_f32_32x32x16_bf16(u1.s, bfr, kZero,0,0,0);\
        EPI(dc, 0)                                                           \
        dc = __builtin_amdgcn_mfma_f32_32x32x16_bf16(u2.s, bfr, kZero,0,0,0);\
        EPI(dn, 1)                                                           \
        dn = __builtin_amdgcn_mfma_f32_32x32x16_bf16(u3.s, bfr, kZero,0,0,0);\
        EPI(dc, 2)                                                           \
        dc = __builtin_amdgcn_mfma_f32_32x32x16_bf16(u4.s, bfr, kZero,0,0,0);\
        EPI(dn, 3)                                                           \
        dn = __builtin_amdgcn_mfma_f32_32x32x16_bf16(u5.s, bfr, kZero,0,0,0);\
        EPI(dc, 4)                                                           \
        EPI(dn, 5)                                                           \
        float s = (S0 + S1) + (S2 + S3);                                     \
        s += __shfl_xor(s, 32);                                              \
        float p = 1.f / (1.f + __expf(-s));                                  \
        if (!half)                                                           \
            OUTP[(size_t)b * 65536 + y * 256 + px] = p;                      \
    }

__global__ __launch_bounds__(256, 4) void conv_p_mfma(
    const float* __restrict__ image, const uint4* __restrict__ wsA,
    float* __restrict__ pout)
{
    CONV_PROLOG
    CONV_COMPUTE(pout)
}

// x8-repeat diagnostic: surfaces conv's true counters in rocprof top-5.
__global__ __launch_bounds__(256, 4) void conv_diag(
    const float* __restrict__ image, const uint4* __restrict__ wsA,
    float* __restrict__ pout)
{
    CONV_PROLOG
    for (int rep = 0; rep < 8; ++rep) {
        asm volatile("" : "+v"(t0), "+v"(t4));   // defeat cross-rep CSE
        CONV_COMPUTE(pout)
    }
}

// mvprop body as macro so the diag can repeat it ------------------------
#define MVPROP_BODY(OUTP, DO_STORE)                                          \
    {                                                                        \
        float v[7][4];                                                       \
        _Pragma("unroll")                                                    \
        for (int i = 0; i < 7; ++i) {                                        \
            v[i][0] = r[i][0]; v[i][1] = r[i][1];                            \
            v[i][2] = r[i][2]; v[i][3] = r[i][3];                            \
        }                                                                    \
        asm volatile("" : "+v"(v[0][0]), "+v"(v[3][2]), "+v"(v[6][3]));      \
        for (int t = 0; t < 20; ++t) {                                       \
            int bf = t & 1;                                                  \
            gT[bf][w][lane] = make_float4(v[0][0], v[0][1], v[0][2], v[0][3]);\
            gB[bf][w][lane] = make_float4(v[6][0], v[6][1], v[6][2], v[6][3]);\
            __syncthreads();                                                 \
            float4 abv = (w > 0) ? gB[bf][w - 1][lane]                       \
                                 : make_float4(SENT, SENT, SENT, SENT);      \
            float4 blw = (w < 7) ? gT[bf][w + 1][lane]                       \
                                 : make_float4(SENT, SENT, SENT, SENT);      \
            float pv0 = abv.x, pv1 = abv.y, pv2 = abv.z, pv3 = abv.w;        \
            _Pragma("unroll")                                                \
            for (int i = 0; i < 7; ++i) {                                    \
                float c0 = v[i][0], c1 = v[i][1], c2 = v[i][2], c3 = v[i][3];\
                float n0, n1, n2, n3;                                        \
                if (i < 6) { n0 = v[i+1][0]; n1 = v[i+1][1];                 \
                             n2 = v[i+1][2]; n3 = v[i+1][3]; }               \
                else       { n0 = blw.x; n1 = blw.y; n2 = blw.z; n3 = blw.w;}\
                float vm0 = fmaxf(pv0, fmaxf(c0, n0));                       \
                float vm1 = fmaxf(pv1, fmaxf(c1, n1));                       \
                float vm2 = fmaxf(pv2, fmaxf(c2, n2));                       \
                float vm3 = fmaxf(pv3, fmaxf(c3, n3));                       \
                float lL = __shfl_up(vm3, 1);                                \
                lL = (lane == 0) ? SENT : lL;                                \
                float rR = __shfl_down(vm0, 1);                              \
                rR = (lane == 63) ? SENT : rR;                               \
                float h0 = fmaxf(lL,  fmaxf(vm0, vm1));                      \
                float h1 = fmaxf(vm0, fmaxf(vm1, vm2));                      \
                float h2 = fmaxf(vm1, fmaxf(vm2, vm3));                      \
                float h3 = fmaxf(vm2, fmaxf(vm3, rR));                       \
                v[i][0] = fmaxf(c0, fmaf(p[i][0], h0 - r[i][0], r[i][0]));   \
                v[i][1] = fmaxf(c1, fmaf(p[i][1], h1 - r[i][1], r[i][1]));   \
                v[i][2] = fmaxf(c2, fmaf(p[i][2], h2 - r[i][2], r[i][2]));   \
                v[i][3] = fmaxf(c3, fmaf(p[i][3], h3 - r[i][3], r[i][3]));   \
                pv0 = c0; pv1 = c1; pv2 = c2; pv3 = c3;                      \
            }                                                                \
        }                                                                    \
        if (DO_STORE) {                                                      \
            const float* occ = image + (size_t)b * 131072;                   \
            _Pragma("unroll")                                                \
            for (int i = 0; i < 7; ++i) {                                    \
                int e = w * 7 + i;                                           \
                if (e >= 20 && e < 36) {                                     \
                    int gy = gy0 + e;                                        \
                    float4 ov = *(const float4*)&occ[gy * 256 + x4];         \
                    float4 o;                                                \
                    o.x = (ov.x > 0.49f) ? v[i][0] : -1.f;                   \
                    o.y = (ov.y > 0.49f) ? v[i][1] : -1.f;                   \
                    o.z = (ov.z > 0.49f) ? v[i][2] : -1.f;                   \
                    o.w = (ov.w > 0.49f) ? v[i][3] : -1.f;                   \
                    *(float4*)&OUTP[(size_t)b * 65536 + gy * 256 + x4] = o;  \
                }                                                            \
            }                                                                \
        }                                                                    \
    }

#define MVPROP_PROLOG                                                        \
    const int tid  = threadIdx.x;                                            \
    const int w    = tid >> 6;                                               \
    const int lane = tid & 63;                                               \
    const int b    = blockIdx.z;                                             \
    const int gy0  = blockIdx.y * 16 - 20;                                   \
    const int x4   = lane * 4;                                               \
    const float* rimg = image + (size_t)b * 131072 + 65536;                  \
    const float* pp   = pbuf  + (size_t)b * 65536;                           \
    float r[7][4], p[7][4];                                                  \
    _Pragma("unroll")                                                        \
    for (int i = 0; i < 7; ++i) {                                            \
        int gy = gy0 + w * 7 + i;                                            \
        if (gy >= 0 && gy < 256) {                                           \
            float4 rv = *(const float4*)&rimg[gy * 256 + x4];                \
            float4 pv = *(const float4*)&pp[gy * 256 + x4];                  \
            r[i][0] = rv.x; r[i][1] = rv.y; r[i][2] = rv.z; r[i][3] = rv.w;  \
            p[i][0] = pv.x; p[i][1] = pv.y; p[i][2] = pv.z; p[i][3] = pv.w;  \
        } else {                                                             \
            r[i][0] = r[i][1] = r[i][2] = r[i][3] = SENT;                    \
            p[i][0] = p[i][1] = p[i][2] = p[i][3] = 0.f;                     \
        }                                                                    \
    }                                                                        \
    __shared__ float4 gT[2][8][64];                                          \
    __shared__ float4 gB[2][8][64];

__global__ __launch_bounds__(512, 2) void mvprop_kernel(
    const float* __restrict__ image, const float* __restrict__ pbuf,
    float* __restrict__ out)
{
    MVPROP_PROLOG
    MVPROP_BODY(out, true)
}

__global__ __launch_bounds__(512, 2) void mvprop_diag(
    const float* __restrict__ image, const float* __restrict__ pbuf,
    float* __restrict__ out)
{
    MVPROP_PROLOG
    for (int rep = 0; rep < 8; ++rep) {
        MVPROP_BODY(out, true)
        __syncthreads();
    }
}

extern "C" void kernel_launch(void* const* d_in, const int* in_sizes, int n_in,
                              void* d_out, int out_size, void* d_ws, size_t ws_size,
                              hipStream_t stream) {
    const float* image = (const float*)d_in[0];  // (16,2,256,256)
    const float* Wh    = (const float*)d_in[1];  // (150,1,3,3)
    const float* bh    = (const float*)d_in[2];  // (150,)
    const float* Wp    = (const float*)d_in[3];  // (1,150,1,1)
    float* out  = (float*)d_out;                 // (16,1,256,256) f32
    float* pbuf = (float*)d_ws;                  // 4 MB scratch for p
    uint4* wsA  = (uint4*)((char*)d_ws + (4 << 20));  // A-fragments + header
    float* convD = (float*)((char*)d_ws + (8u << 20));   // diag dump
    float* mvD   = (float*)((char*)d_ws + (16u << 20));  // diag dump

    pack_a_kernel<<<1, 256, 0, stream>>>(Wh, bh, Wp, wsA);
    conv_p_mfma<<<dim3(8, 64, 16), dim3(256), 0, stream>>>(image, wsA, pbuf);
    mvprop_kernel<<<dim3(1, 16, 16), dim3(512), 0, stream>>>(image, pbuf, out);

    if (ws_size >= (24u << 20)) {   // diagnostics (appended; not load-bearing)
        conv_diag<<<dim3(8, 64, 16), dim3(256), 0, stream>>>(image, wsA, convD);
        mvprop_diag<<<dim3(1, 16, 16), dim3(512), 0, stream>>>(image, pbuf, mvD);
    }
}

// Round 8
// 54.326 us; speedup vs baseline: 6.0208x; 6.0208x over previous
//
#include <hip/hip_runtime.h>
#include <hip/hip_bf16.h>
#include <math.h>

// B=16, H=W=256, 150 hidden channels, K=20 value-iteration steps.
//
// pack_a_kernel: sign-partitions channels by sign(Wp), scales rows by SIGNED
//   Wp, packs MFMA A-frags (6 groups x 32 rows, zero-pad) + nPosG header.
//   Wp*relu(h) == max(Wp*h,0) for Wp>=0, min(Wp*h,0) for Wp<0.
// conv_p_mfma: no LDS, no barriers; A-frags direct from global (L2-resident
//   6KB); 2-deep MFMA/epilogue pipeline. launch_bounds(256,5) -> 5 waves/SIMD.
// mvprop_kernel (R8): 3-phase iteration: (A) vertical max3 rows 1..5 first
//   (ghost LDS reads land underneath), (B) all 14 shuffles issued
//   independently (was 14 serialized round-trips), (C) horizontal max3 +
//   updates. Math identical to the verified R2 kernel.

#define SENT -1e30f

typedef short short8 __attribute__((ext_vector_type(8)));
typedef float f32x16 __attribute__((ext_vector_type(16)));

__device__ __forceinline__ uint32_t pkbf(float lo, float hi) {
    uint32_t r;
    asm("v_cvt_pk_bf16_f32 %0, %1, %2" : "=v"(r) : "v"(lo), "v"(hi));
    return r;
}

__device__ __forceinline__ uint32_t bfu(float f) {
    __hip_bfloat16 h = __float2bfloat16(f);
    ushort u; __builtin_memcpy(&u, &h, 2);
    return (uint32_t)u;
}

__device__ __forceinline__ float max3f(float a, float b, float c) {
    return fmaxf(a, fmaxf(b, c));     // folds to v_max3_f32
}

// ---- setup: sign-partition + scale + pack A fragments. grid=1, block=256.
__global__ void pack_a_kernel(const float* __restrict__ Wh,
                              const float* __restrict__ bh,
                              const float* __restrict__ Wp,
                              uint4* __restrict__ wsA)
{
    __shared__ int scan[256];
    const int tid = threadIdx.x;
    const bool valid = tid < 150;
    float wp = valid ? Wp[tid] : 0.f;
    bool pos = valid && (wp >= 0.f);
    bool neg = valid && (wp < 0.f);

    int v = (pos ? 1 : 0) | ((neg ? 1 : 0) << 16);
    scan[tid] = v;
    __syncthreads();
    for (int off = 1; off < 256; off <<= 1) {
        int x = scan[tid];
        int y = (tid >= off) ? scan[tid - off] : 0;
        __syncthreads();
        scan[tid] = x + y;
        __syncthreads();
    }
    int incl  = scan[tid];
    int total = scan[255];
    int P     = total & 0xffff;
    int rankPos = (incl & 0xffff) - (pos ? 1 : 0);
    int rankNeg = (incl >> 16)    - (neg ? 1 : 0);
    int Ppad  = (P + 31) & ~31;
    int nPosG = Ppad >> 5;
    int newidx = pos ? rankPos : (Ppad + rankNeg);

    if (tid < 384) wsA[tid] = make_uint4(0u, 0u, 0u, 0u);
    if (tid == 0)  ((uint32_t*)(wsA + 384))[0] = (uint32_t)nPosG;
    __syncthreads();

    if (valid) {
        float s  = wp;
        float w0 = Wh[tid*9+0]*s, w1 = Wh[tid*9+1]*s, w2 = Wh[tid*9+2]*s;
        float w3 = Wh[tid*9+3]*s, w4 = Wh[tid*9+4]*s, w5 = Wh[tid*9+5]*s;
        float w6 = Wh[tid*9+6]*s, w7 = Wh[tid*9+7]*s, w8 = Wh[tid*9+8]*s;
        float bb = bh[tid]*s;
        int g = newidx >> 5, col0 = newidx & 31;
        uint4 q;
        q.x = (bfu(w1) << 16) | bfu(w0);
        q.y = (bfu(w3) << 16) | bfu(w2);
        q.z = (bfu(w5) << 16) | bfu(w4);
        q.w = (bfu(w7) << 16) | bfu(w6);
        wsA[g * 64 + col0] = q;                 // half 0: k=0..7
        q.x = (bfu(bb) << 16) | bfu(w8);        // half 1: k=8 tap, k=9 bias
        q.y = 0; q.z = 0; q.w = 0;
        wsA[g * 64 + 32 + col0] = q;
    }
}

#define EPI(D, G)                                                            \
    if ((G) < nPosG) {                                                       \
        S0 += fmaxf(D[0],0.f);  S1 += fmaxf(D[1],0.f);                       \
        S2 += fmaxf(D[2],0.f);  S3 += fmaxf(D[3],0.f);                       \
        S0 += fmaxf(D[4],0.f);  S1 += fmaxf(D[5],0.f);                       \
        S2 += fmaxf(D[6],0.f);  S3 += fmaxf(D[7],0.f);                       \
        S0 += fmaxf(D[8],0.f);  S1 += fmaxf(D[9],0.f);                       \
        S2 += fmaxf(D[10],0.f); S3 += fmaxf(D[11],0.f);                      \
        S0 += fmaxf(D[12],0.f); S1 += fmaxf(D[13],0.f);                      \
        S2 += fmaxf(D[14],0.f); S3 += fmaxf(D[15],0.f);                      \
    } else {                                                                 \
        S0 += fminf(D[0],0.f);  S1 += fminf(D[1],0.f);                       \
        S2 += fminf(D[2],0.f);  S3 += fminf(D[3],0.f);                       \
        S0 += fminf(D[4],0.f);  S1 += fminf(D[5],0.f);                       \
        S2 += fminf(D[6],0.f);  S3 += fminf(D[7],0.f);                       \
        S0 += fminf(D[8],0.f);  S1 += fminf(D[9],0.f);                       \
        S2 += fminf(D[10],0.f); S3 += fminf(D[11],0.f);                      \
        S0 += fminf(D[12],0.f); S1 += fminf(D[13],0.f);                      \
        S2 += fminf(D[14],0.f); S3 += fminf(D[15],0.f);                      \
    }

__global__ __launch_bounds__(256, 5) void conv_p_mfma(
    const float* __restrict__ image, const uint4* __restrict__ wsA,
    float* __restrict__ pout)
{
    const int tid  = threadIdx.x;
    const int wv   = tid >> 6;
    const int lane = tid & 63;
    const int half = lane >> 5;
    const int col0 = lane & 31;
    const int b    = blockIdx.z;
    const int y    = blockIdx.y * 4 + wv;
    const int px   = blockIdx.x * 32 + col0;
    const float* occ = image + (size_t)b * 131072;

    uint4 q0 = wsA[0*64+lane], q1 = wsA[1*64+lane], q2 = wsA[2*64+lane];
    uint4 q3 = wsA[3*64+lane], q4 = wsA[4*64+lane], q5 = wsA[5*64+lane];
    const int nPosG = (int)__builtin_amdgcn_readfirstlane(
        ((const uint32_t*)(wsA + 384))[0]);

    float t0, t1, t2, t3, t4, t5, t6, t7, t8;
    {
        bool x0ok = (px >= 1), x2ok = (px <= 254);
        int xm = px - 1, xp = px + 1;
        bool y0ok = (y >= 1), y2ok = (y <= 254);
        const float* rm = occ + (y - 1) * 256;
        const float* rc = occ + y * 256;
        const float* rp = occ + (y + 1) * 256;
        t0 = (y0ok & x0ok) ? rm[xm] : 0.f;
        t1 =  y0ok         ? rm[px] : 0.f;
        t2 = (y0ok & x2ok) ? rm[xp] : 0.f;
        t3 =  x0ok         ? rc[xm] : 0.f;
        t4 =                 rc[px];
        t5 =  x2ok         ? rc[xp] : 0.f;
        t6 = (y2ok & x0ok) ? rp[xm] : 0.f;
        t7 =  y2ok         ? rp[px] : 0.f;
        t8 = (y2ok & x2ok) ? rp[xp] : 0.f;
    }

    union UA { uint4 q; short8 s; };
    UA u0, u1, u2, u3, u4, u5;
    u0.q = q0; u1.q = q1; u2.q = q2; u3.q = q3; u4.q = q4; u5.q = q5;

    union { uint32_t u[4]; short8 s; } bb;
    bb.u[0] = half ? pkbf(t8, 1.0f) : pkbf(t0, t1);
    bb.u[1] = half ? 0u : pkbf(t2, t3);
    bb.u[2] = half ? 0u : pkbf(t4, t5);
    bb.u[3] = half ? 0u : pkbf(t6, t7);
    short8 bfr = bb.s;

    const f32x16 kZero = {};
    float S0 = 0.f, S1 = 0.f, S2 = 0.f, S3 = 0.f;
    f32x16 dc, dn;
    dc = __builtin_amdgcn_mfma_f32_32x32x16_bf16(u0.s, bfr, kZero, 0, 0, 0);
    dn = __builtin_amdgcn_mfma_f32_32x32x16_bf16(u1.s, bfr, kZero, 0, 0, 0);
    EPI(dc, 0)
    dc = __builtin_amdgcn_mfma_f32_32x32x16_bf16(u2.s, bfr, kZero, 0, 0, 0);
    EPI(dn, 1)
    dn = __builtin_amdgcn_mfma_f32_32x32x16_bf16(u3.s, bfr, kZero, 0, 0, 0);
    EPI(dc, 2)
    dc = __builtin_amdgcn_mfma_f32_32x32x16_bf16(u4.s, bfr, kZero, 0, 0, 0);
    EPI(dn, 3)
    dn = __builtin_amdgcn_mfma_f32_32x32x16_bf16(u5.s, bfr, kZero, 0, 0, 0);
    EPI(dc, 4)
    EPI(dn, 5)

    float s = (S0 + S1) + (S2 + S3);
    s += __shfl_xor(s, 32);

    float p = 1.f / (1.f + __expf(-s));
    if (!half)
        pout[(size_t)b * 65536 + y * 256 + px] = p;
}

__global__ __launch_bounds__(512, 2) void mvprop_kernel(
    const float* __restrict__ image, const float* __restrict__ pbuf,
    float* __restrict__ out)
{
    const int tid  = threadIdx.x;
    const int w    = tid >> 6;          // wave 0..7, owns ext rows 7w..7w+6
    const int lane = tid & 63;          // lane owns cols 4*lane..4*lane+3
    const int b    = blockIdx.z;
    const int gy0  = blockIdx.y * 16 - 20;
    const int x4   = lane * 4;

    const float* rimg = image + (size_t)b * 131072 + 65536;  // channel 1
    const float* pp   = pbuf  + (size_t)b * 65536;

    float v[7][4], r[7][4], p[7][4];
#pragma unroll
    for (int i = 0; i < 7; ++i) {
        int gy = gy0 + w * 7 + i;
        if (gy >= 0 && gy < 256) {
            float4 rv = *(const float4*)&rimg[gy * 256 + x4];
            float4 pv = *(const float4*)&pp[gy * 256 + x4];
            r[i][0] = rv.x; r[i][1] = rv.y; r[i][2] = rv.z; r[i][3] = rv.w;
            p[i][0] = pv.x; p[i][1] = pv.y; p[i][2] = pv.z; p[i][3] = pv.w;
        } else {
            r[i][0] = r[i][1] = r[i][2] = r[i][3] = SENT;
            p[i][0] = p[i][1] = p[i][2] = p[i][3] = 0.f;
        }
        v[i][0] = r[i][0]; v[i][1] = r[i][1];
        v[i][2] = r[i][2]; v[i][3] = r[i][3];
    }

    __shared__ float4 gT[2][8][64];
    __shared__ float4 gB[2][8][64];

    for (int t = 0; t < 20; ++t) {
        int bf = t & 1;
        gT[bf][w][lane] = make_float4(v[0][0], v[0][1], v[0][2], v[0][3]);
        gB[bf][w][lane] = make_float4(v[6][0], v[6][1], v[6][2], v[6][3]);
        __syncthreads();
        // issue ghost reads NOW; consumed ~20 VALU ops later (vm[0], vm[6])
        float4 abv = (w > 0) ? gB[bf][w - 1][lane]
                             : make_float4(SENT, SENT, SENT, SENT);
        float4 blw = (w < 7) ? gT[bf][w + 1][lane]
                             : make_float4(SENT, SENT, SENT, SENT);

        // ---- phase A: vertical 3-max into vm (rows 1..5 first, ghosts last)
        float vm[7][4];
#pragma unroll
        for (int i = 1; i <= 5; ++i) {
            vm[i][0] = max3f(v[i-1][0], v[i][0], v[i+1][0]);
            vm[i][1] = max3f(v[i-1][1], v[i][1], v[i+1][1]);
            vm[i][2] = max3f(v[i-1][2], v[i][2], v[i+1][2]);
            vm[i][3] = max3f(v[i-1][3], v[i][3], v[i+1][3]);
        }
        vm[0][0] = max3f(abv.x, v[0][0], v[1][0]);
        vm[0][1] = max3f(abv.y, v[0][1], v[1][1]);
        vm[0][2] = max3f(abv.z, v[0][2], v[1][2]);
        vm[0][3] = max3f(abv.w, v[0][3], v[1][3]);
        vm[6][0] = max3f(v[5][0], v[6][0], blw.x);
        vm[6][1] = max3f(v[5][1], v[6][1], blw.y);
        vm[6][2] = max3f(v[5][2], v[6][2], blw.z);
        vm[6][3] = max3f(v[5][3], v[6][3], blw.w);

        // ---- phase B: all 14 cross-lane exchanges, issued independently
        float lL[7], rR[7];
#pragma unroll
        for (int i = 0; i < 7; ++i) {
            float a = __shfl_up(vm[i][3], 1);
            lL[i] = (lane == 0) ? SENT : a;
            float c = __shfl_down(vm[i][0], 1);
            rR[i] = (lane == 63) ? SENT : c;
        }

        // ---- phase C: horizontal 3-max + update (pure VALU)
#pragma unroll
        for (int i = 0; i < 7; ++i) {
            float h0 = max3f(lL[i],    vm[i][0], vm[i][1]);
            float h1 = max3f(vm[i][0], vm[i][1], vm[i][2]);
            float h2 = max3f(vm[i][1], vm[i][2], vm[i][3]);
            float h3 = max3f(vm[i][2], vm[i][3], rR[i]);
            v[i][0] = fmaxf(v[i][0], fmaf(p[i][0], h0 - r[i][0], r[i][0]));
            v[i][1] = fmaxf(v[i][1], fmaf(p[i][1], h1 - r[i][1], r[i][1]));
            v[i][2] = fmaxf(v[i][2], fmaf(p[i][2], h2 - r[i][2], r[i][2]));
            v[i][3] = fmaxf(v[i][3], fmaf(p[i][3], h3 - r[i][3], r[i][3]));
        }
    }

    const float* occ = image + (size_t)b * 131072;
#pragma unroll
    for (int i = 0; i < 7; ++i) {
        int e = w * 7 + i;
        if (e >= 20 && e < 36) {
            int gy = gy0 + e;
            float4 ov = *(const float4*)&occ[gy * 256 + x4];
            float4 o;
            o.x = (ov.x > 0.49f) ? v[i][0] : -1.f;
            o.y = (ov.y > 0.49f) ? v[i][1] : -1.f;
            o.z = (ov.z > 0.49f) ? v[i][2] : -1.f;
            o.w = (ov.w > 0.49f) ? v[i][3] : -1.f;
            *(float4*)&out[(size_t)b * 65536 + gy * 256 + x4] = o;
        }
    }
}

extern "C" void kernel_launch(void* const* d_in, const int* in_sizes, int n_in,
                              void* d_out, int out_size, void* d_ws, size_t ws_size,
                              hipStream_t stream) {
    const float* image = (const float*)d_in[0];  // (16,2,256,256)
    const float* Wh    = (const float*)d_in[1];  // (150,1,3,3)
    const float* bh    = (const float*)d_in[2];  // (150,)
    const float* Wp    = (const float*)d_in[3];  // (1,150,1,1)
    float* out  = (float*)d_out;                 // (16,1,256,256) f32
    float* pbuf = (float*)d_ws;                  // 4 MB scratch for p
    uint4* wsA  = (uint4*)((char*)d_ws + (4 << 20));  // A-fragments + header

    pack_a_kernel<<<1, 256, 0, stream>>>(Wh, bh, Wp, wsA);
    conv_p_mfma<<<dim3(8, 64, 16), dim3(256), 0, stream>>>(image, wsA, pbuf);
    mvprop_kernel<<<dim3(1, 16, 16), dim3(512), 0, stream>>>(image, pbuf, out);
}

// Round 9
// 53.762 us; speedup vs baseline: 6.0840x; 1.0105x over previous
//
#include <hip/hip_runtime.h>
#include <hip/hip_bf16.h>
#include <math.h>

// B=16, H=W=256, 150 hidden channels, K=20 value-iteration steps.
//
// pack_a_kernel: sign-partitions channels by sign(Wp), scales rows by SIGNED
//   Wp, packs MFMA A-frags (6 groups x 32 rows, zero-pad) + nPosG header.
//   Wp*relu(h) == max(Wp*h,0) for Wp>=0, min(Wp*h,0) for Wp<0.
// conv_p_mfma (R9): 4 ROWS PER WAVE — amortizes the ~1500-cyc load-to-MFMA
//   front-end stall (measured P ~ 2/3 of conv's 30us) over 4 strips.
//   Per wave: 6 A-frag loads + 18 tap loads up front, then 4x
//   {B-frag -> 6 MFMA serial-acc -> sign-split EPI -> sigmoid -> store}.
// mvprop_kernel: R8 3-phase version (verified).

#define SENT -1e30f

typedef short short8 __attribute__((ext_vector_type(8)));
typedef float f32x16 __attribute__((ext_vector_type(16)));

__device__ __forceinline__ uint32_t pkbf(float lo, float hi) {
    uint32_t r;
    asm("v_cvt_pk_bf16_f32 %0, %1, %2" : "=v"(r) : "v"(lo), "v"(hi));
    return r;
}

__device__ __forceinline__ uint32_t bfu(float f) {
    __hip_bfloat16 h = __float2bfloat16(f);
    ushort u; __builtin_memcpy(&u, &h, 2);
    return (uint32_t)u;
}

__device__ __forceinline__ float max3f(float a, float b, float c) {
    return fmaxf(a, fmaxf(b, c));     // folds to v_max3_f32
}

// ---- setup: sign-partition + scale + pack A fragments. grid=1, block=256.
__global__ void pack_a_kernel(const float* __restrict__ Wh,
                              const float* __restrict__ bh,
                              const float* __restrict__ Wp,
                              uint4* __restrict__ wsA)
{
    __shared__ int scan[256];
    const int tid = threadIdx.x;
    const bool valid = tid < 150;
    float wp = valid ? Wp[tid] : 0.f;
    bool pos = valid && (wp >= 0.f);
    bool neg = valid && (wp < 0.f);

    int v = (pos ? 1 : 0) | ((neg ? 1 : 0) << 16);
    scan[tid] = v;
    __syncthreads();
    for (int off = 1; off < 256; off <<= 1) {
        int x = scan[tid];
        int y = (tid >= off) ? scan[tid - off] : 0;
        __syncthreads();
        scan[tid] = x + y;
        __syncthreads();
    }
    int incl  = scan[tid];
    int total = scan[255];
    int P     = total & 0xffff;
    int rankPos = (incl & 0xffff) - (pos ? 1 : 0);
    int rankNeg = (incl >> 16)    - (neg ? 1 : 0);
    int Ppad  = (P + 31) & ~31;
    int nPosG = Ppad >> 5;
    int newidx = pos ? rankPos : (Ppad + rankNeg);

    if (tid < 384) wsA[tid] = make_uint4(0u, 0u, 0u, 0u);
    if (tid == 0)  ((uint32_t*)(wsA + 384))[0] = (uint32_t)nPosG;
    __syncthreads();

    if (valid) {
        float s  = wp;
        float w0 = Wh[tid*9+0]*s, w1 = Wh[tid*9+1]*s, w2 = Wh[tid*9+2]*s;
        float w3 = Wh[tid*9+3]*s, w4 = Wh[tid*9+4]*s, w5 = Wh[tid*9+5]*s;
        float w6 = Wh[tid*9+6]*s, w7 = Wh[tid*9+7]*s, w8 = Wh[tid*9+8]*s;
        float bb = bh[tid]*s;
        int g = newidx >> 5, col0 = newidx & 31;
        uint4 q;
        q.x = (bfu(w1) << 16) | bfu(w0);
        q.y = (bfu(w3) << 16) | bfu(w2);
        q.z = (bfu(w5) << 16) | bfu(w4);
        q.w = (bfu(w7) << 16) | bfu(w6);
        wsA[g * 64 + col0] = q;                 // half 0: k=0..7
        q.x = (bfu(bb) << 16) | bfu(w8);        // half 1: k=8 tap, k=9 bias
        q.y = 0; q.z = 0; q.w = 0;
        wsA[g * 64 + 32 + col0] = q;
    }
}

#define EPI(D, G)                                                            \
    if ((G) < nPosG) {                                                       \
        S0 += fmaxf(D[0],0.f);  S1 += fmaxf(D[1],0.f);                       \
        S2 += fmaxf(D[2],0.f);  S3 += fmaxf(D[3],0.f);                       \
        S0 += fmaxf(D[4],0.f);  S1 += fmaxf(D[5],0.f);                       \
        S2 += fmaxf(D[6],0.f);  S3 += fmaxf(D[7],0.f);                       \
        S0 += fmaxf(D[8],0.f);  S1 += fmaxf(D[9],0.f);                       \
        S2 += fmaxf(D[10],0.f); S3 += fmaxf(D[11],0.f);                      \
        S0 += fmaxf(D[12],0.f); S1 += fmaxf(D[13],0.f);                      \
        S2 += fmaxf(D[14],0.f); S3 += fmaxf(D[15],0.f);                      \
    } else {                                                                 \
        S0 += fminf(D[0],0.f);  S1 += fminf(D[1],0.f);                       \
        S2 += fminf(D[2],0.f);  S3 += fminf(D[3],0.f);                       \
        S0 += fminf(D[4],0.f);  S1 += fminf(D[5],0.f);                       \
        S2 += fminf(D[6],0.f);  S3 += fminf(D[7],0.f);                       \
        S0 += fminf(D[8],0.f);  S1 += fminf(D[9],0.f);                       \
        S2 += fminf(D[10],0.f); S3 += fminf(D[11],0.f);                      \
        S0 += fminf(D[12],0.f); S1 += fminf(D[13],0.f);                      \
        S2 += fminf(D[14],0.f); S3 += fminf(D[15],0.f);                      \
    }

__global__ __launch_bounds__(256, 4) void conv_p_mfma(
    const float* __restrict__ image, const uint4* __restrict__ wsA,
    float* __restrict__ pout)
{
    const int tid  = threadIdx.x;
    const int wv   = tid >> 6;
    const int lane = tid & 63;
    const int half = lane >> 5;
    const int col0 = lane & 31;
    const int b    = blockIdx.z;
    const int y0   = blockIdx.y * 16 + wv * 4;   // wave owns rows y0..y0+3
    const int px   = blockIdx.x * 32 + col0;     // strip column
    const float* occ = image + (size_t)b * 131072;

    // A fragments (L2/L3-resident 6KB, shared by every block)
    uint4 q0 = wsA[0*64+lane], q1 = wsA[1*64+lane], q2 = wsA[2*64+lane];
    uint4 q3 = wsA[3*64+lane], q4 = wsA[4*64+lane], q5 = wsA[5*64+lane];
    const int nPosG = (int)__builtin_amdgcn_readfirstlane(
        ((const uint32_t*)(wsA + 384))[0]);

    // taps for 4 pixel-rows: need image rows y0-1 .. y0+4, cols px-1,px,px+1
    const bool x0ok = (px >= 1), x2ok = (px <= 254);
    float tm[6], tc[6], tp[6];
#pragma unroll
    for (int rr = 0; rr < 6; ++rr) {
        int yy = y0 - 1 + rr;
        bool yok = (yy >= 0) & (yy < 256);
        const float* base = occ + yy * 256;
        tm[rr] = (yok & x0ok) ? base[px - 1] : 0.f;
        tc[rr] =  yok         ? base[px]     : 0.f;
        tp[rr] = (yok & x2ok) ? base[px + 1] : 0.f;
    }

    union UA { uint4 q; short8 s; };
    UA u0, u1, u2, u3, u4, u5;
    u0.q = q0; u1.q = q1; u2.q = q2; u3.q = q3; u4.q = q4; u5.q = q5;

    const f32x16 kZero = {};
#pragma unroll
    for (int j = 0; j < 4; ++j) {
        // 3x3 taps for pixel (y0+j, px)
        float t0 = tm[j],   t1 = tc[j],   t2 = tp[j];
        float t3 = tm[j+1], t4 = tc[j+1], t5 = tp[j+1];
        float t6 = tm[j+2], t7 = tc[j+2], t8 = tp[j+2];

        // B fragment: half0 -> k=0..7 = t0..t7; half1 -> k=8=t8, k=9=1.0
        union { uint32_t u[4]; short8 s; } bb;
        bb.u[0] = half ? pkbf(t8, 1.0f) : pkbf(t0, t1);
        bb.u[1] = half ? 0u : pkbf(t2, t3);
        bb.u[2] = half ? 0u : pkbf(t4, t5);
        bb.u[3] = half ? 0u : pkbf(t6, t7);
        short8 bfr = bb.s;

        float S0 = 0.f, S1 = 0.f, S2 = 0.f, S3 = 0.f;
        f32x16 dc, dn;
        dc = __builtin_amdgcn_mfma_f32_32x32x16_bf16(u0.s, bfr, kZero, 0, 0, 0);
        dn = __builtin_amdgcn_mfma_f32_32x32x16_bf16(u1.s, bfr, kZero, 0, 0, 0);
        EPI(dc, 0)
        dc = __builtin_amdgcn_mfma_f32_32x32x16_bf16(u2.s, bfr, kZero, 0, 0, 0);
        EPI(dn, 1)
        dn = __builtin_amdgcn_mfma_f32_32x32x16_bf16(u3.s, bfr, kZero, 0, 0, 0);
        EPI(dc, 2)
        dc = __builtin_amdgcn_mfma_f32_32x32x16_bf16(u4.s, bfr, kZero, 0, 0, 0);
        EPI(dn, 3)
        dn = __builtin_amdgcn_mfma_f32_32x32x16_bf16(u5.s, bfr, kZero, 0, 0, 0);
        EPI(dc, 4)
        EPI(dn, 5)

        float s = (S0 + S1) + (S2 + S3);
        s += __shfl_xor(s, 32);   // combine the two half-wave channel sets

        float p = 1.f / (1.f + __expf(-s));
        if (!half)
            pout[(size_t)b * 65536 + (y0 + j) * 256 + px] = p;
    }
}

__global__ __launch_bounds__(512, 2) void mvprop_kernel(
    const float* __restrict__ image, const float* __restrict__ pbuf,
    float* __restrict__ out)
{
    const int tid  = threadIdx.x;
    const int w    = tid >> 6;          // wave 0..7, owns ext rows 7w..7w+6
    const int lane = tid & 63;          // lane owns cols 4*lane..4*lane+3
    const int b    = blockIdx.z;
    const int gy0  = blockIdx.y * 16 - 20;
    const int x4   = lane * 4;

    const float* rimg = image + (size_t)b * 131072 + 65536;  // channel 1
    const float* pp   = pbuf  + (size_t)b * 65536;

    float v[7][4], r[7][4], p[7][4];
#pragma unroll
    for (int i = 0; i < 7; ++i) {
        int gy = gy0 + w * 7 + i;
        if (gy >= 0 && gy < 256) {
            float4 rv = *(const float4*)&rimg[gy * 256 + x4];
            float4 pv = *(const float4*)&pp[gy * 256 + x4];
            r[i][0] = rv.x; r[i][1] = rv.y; r[i][2] = rv.z; r[i][3] = rv.w;
            p[i][0] = pv.x; p[i][1] = pv.y; p[i][2] = pv.z; p[i][3] = pv.w;
        } else {
            r[i][0] = r[i][1] = r[i][2] = r[i][3] = SENT;
            p[i][0] = p[i][1] = p[i][2] = p[i][3] = 0.f;
        }
        v[i][0] = r[i][0]; v[i][1] = r[i][1];
        v[i][2] = r[i][2]; v[i][3] = r[i][3];
    }

    __shared__ float4 gT[2][8][64];
    __shared__ float4 gB[2][8][64];

    for (int t = 0; t < 20; ++t) {
        int bf = t & 1;
        gT[bf][w][lane] = make_float4(v[0][0], v[0][1], v[0][2], v[0][3]);
        gB[bf][w][lane] = make_float4(v[6][0], v[6][1], v[6][2], v[6][3]);
        __syncthreads();
        float4 abv = (w > 0) ? gB[bf][w - 1][lane]
                             : make_float4(SENT, SENT, SENT, SENT);
        float4 blw = (w < 7) ? gT[bf][w + 1][lane]
                             : make_float4(SENT, SENT, SENT, SENT);

        // phase A: vertical 3-max (rows 1..5 first, ghost rows last)
        float vm[7][4];
#pragma unroll
        for (int i = 1; i <= 5; ++i) {
            vm[i][0] = max3f(v[i-1][0], v[i][0], v[i+1][0]);
            vm[i][1] = max3f(v[i-1][1], v[i][1], v[i+1][1]);
            vm[i][2] = max3f(v[i-1][2], v[i][2], v[i+1][2]);
            vm[i][3] = max3f(v[i-1][3], v[i][3], v[i+1][3]);
        }
        vm[0][0] = max3f(abv.x, v[0][0], v[1][0]);
        vm[0][1] = max3f(abv.y, v[0][1], v[1][1]);
        vm[0][2] = max3f(abv.z, v[0][2], v[1][2]);
        vm[0][3] = max3f(abv.w, v[0][3], v[1][3]);
        vm[6][0] = max3f(v[5][0], v[6][0], blw.x);
        vm[6][1] = max3f(v[5][1], v[6][1], blw.y);
        vm[6][2] = max3f(v[5][2], v[6][2], blw.z);
        vm[6][3] = max3f(v[5][3], v[6][3], blw.w);

        // phase B: all 14 cross-lane exchanges, issued independently
        float lL[7], rR[7];
#pragma unroll
        for (int i = 0; i < 7; ++i) {
            float a = __shfl_up(vm[i][3], 1);
            lL[i] = (lane == 0) ? SENT : a;
            float c = __shfl_down(vm[i][0], 1);
            rR[i] = (lane == 63) ? SENT : c;
        }

        // phase C: horizontal 3-max + update (pure VALU)
#pragma unroll
        for (int i = 0; i < 7; ++i) {
            float h0 = max3f(lL[i],    vm[i][0], vm[i][1]);
            float h1 = max3f(vm[i][0], vm[i][1], vm[i][2]);
            float h2 = max3f(vm[i][1], vm[i][2], vm[i][3]);
            float h3 = max3f(vm[i][2], vm[i][3], rR[i]);
            v[i][0] = fmaxf(v[i][0], fmaf(p[i][0], h0 - r[i][0], r[i][0]));
            v[i][1] = fmaxf(v[i][1], fmaf(p[i][1], h1 - r[i][1], r[i][1]));
            v[i][2] = fmaxf(v[i][2], fmaf(p[i][2], h2 - r[i][2], r[i][2]));
            v[i][3] = fmaxf(v[i][3], fmaf(p[i][3], h3 - r[i][3], r[i][3]));
        }
    }

    const float* occ = image + (size_t)b * 131072;
#pragma unroll
    for (int i = 0; i < 7; ++i) {
        int e = w * 7 + i;
        if (e >= 20 && e < 36) {
            int gy = gy0 + e;
            float4 ov = *(const float4*)&occ[gy * 256 + x4];
            float4 o;
            o.x = (ov.x > 0.49f) ? v[i][0] : -1.f;
            o.y = (ov.y > 0.49f) ? v[i][1] : -1.f;
            o.z = (ov.z > 0.49f) ? v[i][2] : -1.f;
            o.w = (ov.w > 0.49f) ? v[i][3] : -1.f;
            *(float4*)&out[(size_t)b * 65536 + gy * 256 + x4] = o;
        }
    }
}

extern "C" void kernel_launch(void* const* d_in, const int* in_sizes, int n_in,
                              void* d_out, int out_size, void* d_ws, size_t ws_size,
                              hipStream_t stream) {
    const float* image = (const float*)d_in[0];  // (16,2,256,256)
    const float* Wh    = (const float*)d_in[1];  // (150,1,3,3)
    const float* bh    = (const float*)d_in[2];  // (150,)
    const float* Wp    = (const float*)d_in[3];  // (1,150,1,1)
    float* out  = (float*)d_out;                 // (16,1,256,256) f32
    float* pbuf = (float*)d_ws;                  // 4 MB scratch for p
    uint4* wsA  = (uint4*)((char*)d_ws + (4 << 20));  // A-fragments + header

    pack_a_kernel<<<1, 256, 0, stream>>>(Wh, bh, Wp, wsA);
    conv_p_mfma<<<dim3(8, 16, 16), dim3(256), 0, stream>>>(image, wsA, pbuf);
    mvprop_kernel<<<dim3(1, 16, 16), dim3(512), 0, stream>>>(image, pbuf, out);
}